// Round 2
// baseline (2897.777 us; speedup 1.0000x reference)
//
#include <hip/hip_runtime.h>

// ---------------- types / helpers ----------------
typedef unsigned short u16;
typedef unsigned int   u32;
typedef __bf16 bf16x8 __attribute__((ext_vector_type(8)));
typedef float  f32x4  __attribute__((ext_vector_type(4)));

__device__ __forceinline__ u16 f2bf(float f) {
    u32 u = __builtin_bit_cast(u32, f);
    u = u + 0x7fffu + ((u >> 16) & 1u);
    return (u16)(u >> 16);
}
__device__ __forceinline__ float bf2f(u16 u) { return __builtin_bit_cast(float, ((u32)u) << 16); }
__device__ __forceinline__ u32 pack2(float x, float y) { return (u32)f2bf(x) | ((u32)f2bf(y) << 16); }

#define NN 100000
#define EE 400000
#define DP 320   // padded D (300 -> 320)
#define HP 640   // padded 2D (600 -> 640)

// ---------------- preprocessing ----------------
__global__ void count_deg(const int* __restrict__ ei, int* __restrict__ deg, int E) {
    int e = blockIdx.x * 256 + threadIdx.x;
    if (e < E) atomicAdd(&deg[ei[E + e]], 1);
}

__global__ void scan1(const int* __restrict__ deg, int* __restrict__ out, int* __restrict__ bsums, int n) {
    __shared__ int lds[1024];
    int t = threadIdx.x;
    int i = blockIdx.x * 1024 + t;
    int v = (i < n) ? deg[i] : 0;
    lds[t] = v;
    __syncthreads();
    for (int d = 1; d < 1024; d <<= 1) {
        int add = (t >= d) ? lds[t - d] : 0;
        __syncthreads();
        lds[t] += add;
        __syncthreads();
    }
    if (i < n) out[i] = lds[t] - v;   // exclusive
    if (t == 1023) bsums[blockIdx.x] = lds[t];
}

__global__ void scan2(int* __restrict__ bsums, int nb) {
    __shared__ int lds[128];
    int t = threadIdx.x;
    int v = (t < nb) ? bsums[t] : 0;
    lds[t] = v;
    __syncthreads();
    for (int d = 1; d < 128; d <<= 1) {
        int add = (t >= d) ? lds[t - d] : 0;
        __syncthreads();
        lds[t] += add;
        __syncthreads();
    }
    if (t < nb) bsums[t] = lds[t] - v;
}

__global__ void scan3(int* __restrict__ out, const int* __restrict__ bsums, int n, int etot) {
    int i = blockIdx.x * 1024 + threadIdx.x;
    if (i < n) out[i] += bsums[blockIdx.x];
    else if (i == n) out[i] = etot;
}

__global__ void fill_csr(const int* __restrict__ ei, const int* __restrict__ ea,
                         int* __restrict__ cursors, u32* __restrict__ vals, int E) {
    int e = blockIdx.x * 256 + threadIdx.x;
    if (e >= E) return;
    int dst = ei[E + e];
    int src = ei[e];
    u32 code = (u32)((ea[e*4] & 1) | ((ea[e*4+1] & 1) << 1) | ((ea[e*4+2] & 1) << 2) | ((ea[e*4+3] & 1) << 3));
    int pos = atomicAdd(&cursors[dst], 1);
    vals[pos] = ((u32)src << 4) | code;
}

// weights -> transposed padded bf16 (B^T layout for MFMA B-operand)
__global__ void conv_w1(const float* __restrict__ w, u16* __restrict__ wt) {
    // w: [5][300][600] -> wt: [5][640][320]  (wt[l][n][k] = w[l][k][n])
    int id = blockIdx.x * 256 + threadIdx.x;
    if (id >= 5 * HP * DP) return;
    int l = id / (HP * DP);
    int rem = id - l * (HP * DP);
    int n = rem / DP;
    int k = rem - n * DP;
    u16 v = 0;
    if (n < 600 && k < 300) v = f2bf(w[((size_t)l * 300 + k) * 600 + n]);
    wt[id] = v;
}
__global__ void conv_w2(const float* __restrict__ w, u16* __restrict__ wt) {
    // w: [5][600][300] -> wt: [5][320][640]
    int id = blockIdx.x * 256 + threadIdx.x;
    if (id >= 5 * DP * HP) return;
    int l = id / (DP * HP);
    int rem = id - l * (DP * HP);
    int n = rem / HP;
    int k = rem - n * HP;
    u16 v = 0;
    if (n < 300 && k < 600) v = f2bf(w[((size_t)l * 600 + k) * 300 + n]);
    wt[id] = v;
}

// atom encoder: h0[i][d] = sum_f atom_tables[f][x[i][f]][d]  (fp32 raw state)
__global__ void atom_enc(const int* __restrict__ x, const float* __restrict__ at, float* __restrict__ h) {
    const int i = blockIdx.x;
    const int d = threadIdx.x; // 0..319
    __shared__ int xi[7];
    if (d < 7) xi[d] = x[i * 7 + d];
    __syncthreads();
    float s = 0.f;
    if (d < 300) {
        #pragma unroll
        for (int f = 0; f < 7; ++f) s += at[(f * 119 + xi[f]) * 300 + d];
    }
    h[(size_t)i * DP + d] = s;
}

// per-layer bond embedding table: 16 codes + self-loop (index 16)
__global__ void bond_enc(const float* __restrict__ bt, float* __restrict__ emb) {
    const int c = blockIdx.x;  // 0..16
    const int d = threadIdx.x; // 0..319
    float s = 0.f;
    if (d < 300) {
        if (c < 16) {
            #pragma unroll
            for (int f = 0; f < 4; ++f) s += bt[(f * 6 + ((c >> f) & 1)) * 300 + d];
        } else {
            s = bt[4 * 300 + d];  // bond[0][4]
            #pragma unroll
            for (int f = 1; f < 4; ++f) s += bt[f * 6 * 300 + d];
        }
    }
    emb[c * DP + d] = s;
}

__global__ void init_ss(float* __restrict__ scale, float* __restrict__ shift) {
    int d = threadIdx.x;
    scale[d] = 1.f; shift[d] = 0.f;
}

// stats -> BN (scale, shift)
__global__ void bn_ss(const float* __restrict__ stats, const float* __restrict__ gamma,
                      const float* __restrict__ beta, float* __restrict__ scale,
                      float* __restrict__ shift, int n) {
    int d = threadIdx.x;
    float sc = 0.f, sh = 0.f;
    if (d < 300) {
        float inv_n = 1.0f / (float)n;
        float mu = stats[d] * inv_n;
        float var = stats[DP + d] * inv_n - mu * mu;
        float inv = 1.0f / sqrtf(var + 1e-5f);
        sc = gamma[d] * inv;
        sh = beta[d] - mu * sc;
    }
    scale[d] = sc; shift[d] = sh;
}

// ---------------- aggregation: one wave per node ----------------
// agg[i] = y(h[i]) + self_emb + sum_edges ( y(h[src]) + emb16[code] ),
// where y(x) = relu?(scale*x + shift)   (BN of previous layer applied on the fly)
// h is fp32 raw (pre-BN) state.
__global__ void aggregate(const float* __restrict__ hraw,
                          const float* __restrict__ scale, const float* __restrict__ shift,
                          const int do_relu,
                          const float* __restrict__ emb,
                          const int* __restrict__ offs, const u32* __restrict__ vals,
                          u16* __restrict__ agg, const int n) {
    const int wid = (int)((blockIdx.x * (size_t)blockDim.x + threadIdx.x) >> 6);
    const int lane = threadIdx.x & 63;
    if (wid >= n) return;
    const int j0 = lane, j1 = lane + 64, j2 = lane + 128;
    const bool has2 = (lane < 32);

    const float2 sc0 = *(const float2*)(scale + 2 * j0);
    const float2 sh0 = *(const float2*)(shift + 2 * j0);
    const float2 sc1 = *(const float2*)(scale + 2 * j1);
    const float2 sh1 = *(const float2*)(shift + 2 * j1);
    float2 sc2 = make_float2(0.f, 0.f), sh2 = make_float2(0.f, 0.f);
    if (has2) { sc2 = *(const float2*)(scale + 2 * j2); sh2 = *(const float2*)(shift + 2 * j2); }

    float a0x = 0.f, a0y = 0.f, a1x = 0.f, a1y = 0.f, a2x = 0.f, a2y = 0.f;

    auto accum = [&](int srcrow, const float* erow) {
        const float* row = hraw + (size_t)srcrow * DP;
        float2 u0 = *(const float2*)(row + 2 * j0);
        float2 u1 = *(const float2*)(row + 2 * j1);
        float2 u2 = has2 ? *(const float2*)(row + 2 * j2) : make_float2(0.f, 0.f);
        float2 e0 = *(const float2*)(erow + 2 * j0);
        float2 e1 = *(const float2*)(erow + 2 * j1);
        float2 e2 = has2 ? *(const float2*)(erow + 2 * j2) : make_float2(0.f, 0.f);
        float v;
        v = fmaf(sc0.x, u0.x, sh0.x); if (do_relu) v = fmaxf(v, 0.f); a0x += v + e0.x;
        v = fmaf(sc0.y, u0.y, sh0.y); if (do_relu) v = fmaxf(v, 0.f); a0y += v + e0.y;
        v = fmaf(sc1.x, u1.x, sh1.x); if (do_relu) v = fmaxf(v, 0.f); a1x += v + e1.x;
        v = fmaf(sc1.y, u1.y, sh1.y); if (do_relu) v = fmaxf(v, 0.f); a1y += v + e1.y;
        if (has2) {
            v = fmaf(sc2.x, u2.x, sh2.x); if (do_relu) v = fmaxf(v, 0.f); a2x += v + e2.x;
            v = fmaf(sc2.y, u2.y, sh2.y); if (do_relu) v = fmaxf(v, 0.f); a2y += v + e2.y;
        }
    };

    accum(wid, emb + 16 * DP);            // self loop
    const int s = offs[wid], t = offs[wid + 1];
    for (int e = s; e < t; ++e) {
        u32 v = vals[e];
        accum((int)(v >> 4), emb + (v & 15u) * DP);
    }

    u32* out = (u32*)agg + (size_t)wid * (DP / 2);
    out[j0] = pack2(a0x, a0y);
    out[j1] = pack2(a1x, a1y);
    if (has2) out[j2] = pack2(a2x, a2y);
}

// ---------------- GEMM: C[M][NP] = A[M][KP] * Wt[NP][KP]^T (+bias, relu, stats) ----------------
#define BM 128
#define BN 64

template<bool RELU, bool STATS, bool F32OUT>
__global__ __launch_bounds__(256) void gemm_bt(
    const u16* __restrict__ A, int KP,
    const u16* __restrict__ Wt,
    const float* __restrict__ bias, int bias_n,
    u16* __restrict__ Cb, float* __restrict__ Cf, int NP, int M,
    float* __restrict__ s1g, float* __restrict__ s2g) {

    __shared__ __align__(16) u16 a_lds[4 * 128 * 8];
    __shared__ __align__(16) u16 b_lds[4 * 64 * 8];
    const int tid = threadIdx.x;
    const int bm = blockIdx.x * BM;
    const int bn = blockIdx.y * BN;
    const int wave = tid >> 6;
    const int lane = tid & 63;
    const int wm = (wave >> 1) * 64;
    const int wn = (wave & 1) * 32;
    const int l15 = lane & 15;
    const int q = lane >> 4;

    f32x4 acc[4][2];
    const f32x4 zero4 = {0.f, 0.f, 0.f, 0.f};
    #pragma unroll
    for (int i = 0; i < 4; ++i)
        #pragma unroll
        for (int j = 0; j < 2; ++j) acc[i][j] = zero4;

    const int arow0 = tid >> 2;   // 0..63
    const int aq = tid & 3;
    const int kTiles = KP >> 5;

    for (int kt = 0; kt < kTiles; ++kt) {
        const int k0 = kt << 5;
        uint4 av0, av1, bv;
        {
            const int r0 = bm + arow0;
            const int r1 = r0 + 64;
            uint4 z; z.x = z.y = z.z = z.w = 0;
            av0 = (r0 < M) ? *(const uint4*)(A + (size_t)r0 * KP + k0 + aq * 8) : z;
            av1 = (r1 < M) ? *(const uint4*)(A + (size_t)r1 * KP + k0 + aq * 8) : z;
            bv  = *(const uint4*)(Wt + (size_t)(bn + arow0) * KP + k0 + aq * 8);
        }
        __syncthreads();
        *(uint4*)&a_lds[(aq * 128 + arow0) * 8] = av0;
        *(uint4*)&a_lds[(aq * 128 + arow0 + 64) * 8] = av1;
        *(uint4*)&b_lds[(aq * 64 + arow0) * 8] = bv;
        __syncthreads();

        bf16x8 af[4], bfr[2];
        #pragma unroll
        for (int im = 0; im < 4; ++im) {
            uint4 t = *(const uint4*)&a_lds[((size_t)q * 128 + wm + im * 16 + l15) * 8];
            af[im] = __builtin_bit_cast(bf16x8, t);
        }
        #pragma unroll
        for (int in = 0; in < 2; ++in) {
            uint4 t = *(const uint4*)&b_lds[((size_t)q * 64 + wn + in * 16 + l15) * 8];
            bfr[in] = __builtin_bit_cast(bf16x8, t);
        }
        #pragma unroll
        for (int im = 0; im < 4; ++im)
            #pragma unroll
            for (int in = 0; in < 2; ++in)
                acc[im][in] = __builtin_amdgcn_mfma_f32_16x16x32_bf16(af[im], bfr[in], acc[im][in], 0, 0, 0);
    }

    // epilogue: C/D layout col = lane&15, row = (lane>>4)*4 + r
    #pragma unroll
    for (int in = 0; in < 2; ++in) {
        const int col = bn + wn + in * 16 + l15;
        float b = 0.f;
        if (col < bias_n) b = bias[col];
        float s1 = 0.f, s2 = 0.f;
        #pragma unroll
        for (int im = 0; im < 4; ++im) {
            #pragma unroll
            for (int r = 0; r < 4; ++r) {
                const int row = bm + wm + im * 16 + q * 4 + r;
                if (row < M) {
                    float v = acc[im][in][r] + b;
                    if (RELU) v = fmaxf(v, 0.f);
                    if (F32OUT) Cf[(size_t)row * NP + col] = v;
                    else        Cb[(size_t)row * NP + col] = f2bf(v);
                    if (STATS) { s1 += v; s2 += v * v; }
                }
            }
        }
        if (STATS) {
            s1 += __shfl_xor(s1, 16); s1 += __shfl_xor(s1, 32);
            s2 += __shfl_xor(s2, 16); s2 += __shfl_xor(s2, 32);
            if (q == 0) { atomicAdd(&s1g[col], s1); atomicAdd(&s2g[col], s2); }
        }
    }
}

// final: d_out[i][d] = scale[d]*raw[i][d] + shift[d]  (no relu, fp32 in/out)
__global__ void finalize(const float* __restrict__ hraw, const float* __restrict__ scale,
                         const float* __restrict__ shift, float* __restrict__ out) {
    const int i = blockIdx.x;
    const int d = threadIdx.x;
    if (d < 300) {
        float x = hraw[(size_t)i * DP + d];
        out[(size_t)i * 300 + d] = fmaf(scale[d], x, shift[d]);
    }
}

// ---------------- launcher ----------------
extern "C" void kernel_launch(void* const* d_in, const int* in_sizes, int n_in,
                              void* d_out, int out_size, void* d_ws, size_t ws_size,
                              hipStream_t stream) {
    const int N = NN, E = EE, L = 5;
    const int*   x     = (const int*)d_in[0];
    const int*   ei    = (const int*)d_in[1];
    const int*   ea    = (const int*)d_in[2];
    const float* at    = (const float*)d_in[3];
    const float* bt    = (const float*)d_in[4];
    const float* w1    = (const float*)d_in[5];
    const float* b1    = (const float*)d_in[6];
    const float* w2    = (const float*)d_in[7];
    const float* b2    = (const float*)d_in[8];
    const float* gamma = (const float*)d_in[9];
    const float* beta  = (const float*)d_in[10];
    float* out = (float*)d_out;

    char* ws = (char*)d_ws;
    size_t off = 0;
    auto alloc = [&](size_t bytes) { char* p = ws + off; off = (off + bytes + 255) & ~(size_t)255; return p; };
    float* buf_h  = (float*)alloc((size_t)N * DP * 4);   // fp32 raw (pre-BN) state
    u16* buf_agg  = (u16*)alloc((size_t)N * DP * 2);
    u16* buf_hid  = (u16*)alloc((size_t)N * HP * 2);
    u16* w1t      = (u16*)alloc((size_t)5 * HP * DP * 2);
    u16* w2t      = (u16*)alloc((size_t)5 * DP * HP * 2);
    int* deg      = (int*)alloc((size_t)N * 4);
    int* offs     = (int*)alloc((size_t)(N + 1) * 4);
    int* cursors  = (int*)alloc((size_t)N * 4);
    u32* vals     = (u32*)alloc((size_t)E * 4);
    int* bsums    = (int*)alloc(128 * 4);
    float* emb    = (float*)alloc(17 * DP * 4);
    float* stats  = (float*)alloc(2 * DP * 4);
    float* scale  = (float*)alloc(DP * 4);
    float* shift  = (float*)alloc(DP * 4);

    // CSR build (once per call; reused by all 5 layers)
    (void)hipMemsetAsync(deg, 0, (size_t)N * 4, stream);
    count_deg<<<(E + 255) / 256, 256, 0, stream>>>(ei, deg, E);
    const int nb = (N + 1023) / 1024;
    scan1<<<nb, 1024, 0, stream>>>(deg, offs, bsums, N);
    scan2<<<1, 128, 0, stream>>>(bsums, nb);
    scan3<<<(N + 1 + 1023) / 1024, 1024, 0, stream>>>(offs, bsums, N, E);
    (void)hipMemcpyAsync(cursors, offs, (size_t)N * 4, hipMemcpyDeviceToDevice, stream);
    fill_csr<<<(E + 255) / 256, 256, 0, stream>>>(ei, ea, cursors, vals, E);

    // weights -> bf16 transposed padded
    conv_w1<<<(5 * HP * DP + 255) / 256, 256, 0, stream>>>(w1, w1t);
    conv_w2<<<(5 * DP * HP + 255) / 256, 256, 0, stream>>>(w2, w2t);

    // atom encoder + identity BN for layer 0
    atom_enc<<<N, DP, 0, stream>>>(x, at, buf_h);
    init_ss<<<1, DP, 0, stream>>>(scale, shift);

    const int MB = (N + BM - 1) / BM; // 782
    for (int l = 0; l < L; ++l) {
        bond_enc<<<17, DP, 0, stream>>>(bt + (size_t)l * 4 * 6 * 300, emb);
        aggregate<<<(N * 64 + 255) / 256, 256, 0, stream>>>(
            buf_h, scale, shift, (l > 0) ? 1 : 0, emb, offs, vals, buf_agg, N);
        gemm_bt<true, false, false><<<dim3(MB, HP / BN), 256, 0, stream>>>(
            buf_agg, DP, w1t + (size_t)l * HP * DP, b1 + (size_t)l * 600, 600,
            buf_hid, nullptr, HP, N, nullptr, nullptr);
        (void)hipMemsetAsync(stats, 0, 2 * DP * 4, stream);
        gemm_bt<false, true, true><<<dim3(MB, DP / BN), 256, 0, stream>>>(
            buf_hid, HP, w2t + (size_t)l * DP * HP, b2 + (size_t)l * 300, 300,
            nullptr, buf_h, DP, N, stats, stats + DP);
        bn_ss<<<1, DP, 0, stream>>>(stats, gamma + (size_t)l * 300, beta + (size_t)l * 300, scale, shift, N);
    }
    finalize<<<N, DP, 0, stream>>>(buf_h, scale, shift, out);
}

// Round 3
// 2149.733 us; speedup vs baseline: 1.3480x; 1.3480x over previous
//
#include <hip/hip_runtime.h>

// ---------------- types / helpers ----------------
typedef unsigned short u16;
typedef unsigned int   u32;
typedef __bf16 bf16x8 __attribute__((ext_vector_type(8)));
typedef float  f32x4  __attribute__((ext_vector_type(4)));

__device__ __forceinline__ u16 f2bf(float f) {
    u32 u = __builtin_bit_cast(u32, f);
    u = u + 0x7fffu + ((u >> 16) & 1u);
    return (u16)(u >> 16);
}
__device__ __forceinline__ float bflo(u32 u) { return __builtin_bit_cast(float, u << 16); }
__device__ __forceinline__ float bfhi(u32 u) { return __builtin_bit_cast(float, u & 0xffff0000u); }
__device__ __forceinline__ u32 pack2(float x, float y) { return (u32)f2bf(x) | ((u32)f2bf(y) << 16); }

#define NN 100000
#define EE 400000
#define DP 320   // padded D (300 -> 320)
#define HP 640   // padded 2D (600 -> 640)

// ---------------- preprocessing (unchanged from round 2) ----------------
__global__ void count_deg(const int* __restrict__ ei, int* __restrict__ deg, int E) {
    int e = blockIdx.x * 256 + threadIdx.x;
    if (e < E) atomicAdd(&deg[ei[E + e]], 1);
}

__global__ void scan1(const int* __restrict__ deg, int* __restrict__ out, int* __restrict__ bsums, int n) {
    __shared__ int lds[1024];
    int t = threadIdx.x;
    int i = blockIdx.x * 1024 + t;
    int v = (i < n) ? deg[i] : 0;
    lds[t] = v;
    __syncthreads();
    for (int d = 1; d < 1024; d <<= 1) {
        int add = (t >= d) ? lds[t - d] : 0;
        __syncthreads();
        lds[t] += add;
        __syncthreads();
    }
    if (i < n) out[i] = lds[t] - v;   // exclusive
    if (t == 1023) bsums[blockIdx.x] = lds[t];
}

__global__ void scan2(int* __restrict__ bsums, int nb) {
    __shared__ int lds[128];
    int t = threadIdx.x;
    int v = (t < nb) ? bsums[t] : 0;
    lds[t] = v;
    __syncthreads();
    for (int d = 1; d < 128; d <<= 1) {
        int add = (t >= d) ? lds[t - d] : 0;
        __syncthreads();
        lds[t] += add;
        __syncthreads();
    }
    if (t < nb) bsums[t] = lds[t] - v;
}

__global__ void scan3(int* __restrict__ out, const int* __restrict__ bsums, int n, int etot) {
    int i = blockIdx.x * 1024 + threadIdx.x;
    if (i < n) out[i] += bsums[blockIdx.x];
    else if (i == n) out[i] = etot;
}

__global__ void fill_csr(const int* __restrict__ ei, const int* __restrict__ ea,
                         int* __restrict__ cursors, u32* __restrict__ vals, int E) {
    int e = blockIdx.x * 256 + threadIdx.x;
    if (e >= E) return;
    int dst = ei[E + e];
    int src = ei[e];
    u32 code = (u32)((ea[e*4] & 1) | ((ea[e*4+1] & 1) << 1) | ((ea[e*4+2] & 1) << 2) | ((ea[e*4+3] & 1) << 3));
    int pos = atomicAdd(&cursors[dst], 1);
    vals[pos] = ((u32)src << 4) | code;
}

// weights -> transposed padded bf16 (B^T layout for MFMA B-operand)
__global__ void conv_w1(const float* __restrict__ w, u16* __restrict__ wt) {
    // w: [5][300][600] -> wt: [5][640][320]  (wt[l][n][k] = w[l][k][n])
    int id = blockIdx.x * 256 + threadIdx.x;
    if (id >= 5 * HP * DP) return;
    int l = id / (HP * DP);
    int rem = id - l * (HP * DP);
    int n = rem / DP;
    int k = rem - n * DP;
    u16 v = 0;
    if (n < 600 && k < 300) v = f2bf(w[((size_t)l * 300 + k) * 600 + n]);
    wt[id] = v;
}
__global__ void conv_w2(const float* __restrict__ w, u16* __restrict__ wt) {
    // w: [5][600][300] -> wt: [5][320][640]
    int id = blockIdx.x * 256 + threadIdx.x;
    if (id >= 5 * DP * HP) return;
    int l = id / (DP * HP);
    int rem = id - l * (DP * HP);
    int n = rem / HP;
    int k = rem - n * HP;
    u16 v = 0;
    if (n < 300 && k < 600) v = f2bf(w[((size_t)l * 600 + k) * 300 + n]);
    wt[id] = v;
}

// atom encoder -> y bf16 (layer-0 "post-BN" state is just the embedding sum)
__global__ void atom_enc(const int* __restrict__ x, const float* __restrict__ at, u16* __restrict__ y) {
    const int i = blockIdx.x;
    const int d = threadIdx.x; // 0..319
    __shared__ int xi[7];
    if (d < 7) xi[d] = x[i * 7 + d];
    __syncthreads();
    u16 v = 0;
    if (d < 300) {
        float s = 0.f;
        #pragma unroll
        for (int f = 0; f < 7; ++f) s += at[(f * 119 + xi[f]) * 300 + d];
        v = f2bf(s);
    }
    y[(size_t)i * DP + d] = v;
}

// per-layer bond embedding table: 16 codes + self-loop (index 16)
__global__ void bond_enc(const float* __restrict__ bt, float* __restrict__ emb) {
    const int c = blockIdx.x;  // 0..16
    const int d = threadIdx.x; // 0..319
    float s = 0.f;
    if (d < 300) {
        if (c < 16) {
            #pragma unroll
            for (int f = 0; f < 4; ++f) s += bt[(f * 6 + ((c >> f) & 1)) * 300 + d];
        } else {
            s = bt[4 * 300 + d];  // bond[0][4]
            #pragma unroll
            for (int f = 1; f < 4; ++f) s += bt[f * 6 * 300 + d];
        }
    }
    emb[c * DP + d] = s;
}

// stats -> BN (scale, shift)
__global__ void bn_ss(const float* __restrict__ stats, const float* __restrict__ gamma,
                      const float* __restrict__ beta, float* __restrict__ scale,
                      float* __restrict__ shift, int n) {
    int d = threadIdx.x;
    float sc = 0.f, sh = 0.f;
    if (d < 300) {
        float inv_n = 1.0f / (float)n;
        float mu = stats[d] * inv_n;
        float var = stats[DP + d] * inv_n - mu * mu;
        float inv = 1.0f / sqrtf(var + 1e-5f);
        sc = gamma[d] * inv;
        sh = beta[d] - mu * sc;
    }
    scale[d] = sc; shift[d] = sh;
}

// y[i][d] = bf16(relu(scale*h_raw + shift))   (pads: scale=shift=0, h pad=0 -> 0)
__global__ void bn_apply(const float* __restrict__ hraw, const float* __restrict__ scale,
                         const float* __restrict__ shift, u16* __restrict__ y) {
    const int i = blockIdx.x;
    const int d = threadIdx.x;
    float v = fmaf(scale[d], hraw[(size_t)i * DP + d], shift[d]);
    y[(size_t)i * DP + d] = f2bf(fmaxf(v, 0.f));
}

// ---------------- aggregation: one wave per node, bf16 y gathers ----------------
// agg[i] = y[i] + self_emb + sum_edges ( y[src] + emb16[code] )
__global__ void aggregate(const u16* __restrict__ y,
                          const float* __restrict__ emb,
                          const int* __restrict__ offs, const u32* __restrict__ vals,
                          u16* __restrict__ agg, const int n) {
    const int wid = (int)((blockIdx.x * (size_t)blockDim.x + threadIdx.x) >> 6);
    const int lane = threadIdx.x & 63;
    if (wid >= n) return;
    const int j0 = lane, j1 = lane + 64, j2 = lane + 128;
    const bool has2 = (lane < 32);

    float a0x = 0.f, a0y = 0.f, a1x = 0.f, a1y = 0.f, a2x = 0.f, a2y = 0.f;

    auto accum = [&](int srcrow, const float* erow) {
        const u32* row = (const u32*)y + (size_t)srcrow * (DP / 2);
        u32 u0 = row[j0], u1 = row[j1];
        u32 u2 = has2 ? row[j2] : 0u;
        float2 e0 = *(const float2*)(erow + 2 * j0);
        float2 e1 = *(const float2*)(erow + 2 * j1);
        a0x += bflo(u0) + e0.x;  a0y += bfhi(u0) + e0.y;
        a1x += bflo(u1) + e1.x;  a1y += bfhi(u1) + e1.y;
        if (has2) {
            float2 e2 = *(const float2*)(erow + 2 * j2);
            a2x += bflo(u2) + e2.x;  a2y += bfhi(u2) + e2.y;
        }
    };

    accum(wid, emb + 16 * DP);            // self loop
    const int s = offs[wid], t = offs[wid + 1];
    for (int e = s; e < t; ++e) {
        u32 v = vals[e];
        accum((int)(v >> 4), emb + (v & 15u) * DP);
    }

    u32* out = (u32*)agg + (size_t)wid * (DP / 2);
    out[j0] = pack2(a0x, a0y);
    out[j1] = pack2(a1x, a1y);
    if (has2) out[j2] = pack2(a2x, a2y);
}

// ---------------- fused MLP: h_raw = (relu(agg@W1+b1))@W2 + b2, + BN stats ----------------
// block: 128 rows x 512 threads (8 waves). hid never leaves LDS.
#define ASTR 328   // A LDS row stride (u16): 656B -> 2-way banks, 16B aligned
#define HSTR 40    // hidT / W2-slice row stride (u16): 80B -> 2-way banks

__global__ __launch_bounds__(512, 2) void fused_mlp(
    const u16* __restrict__ A,      // agg [N][320] bf16
    const u16* __restrict__ W1t,    // [640][320] bf16 (W1^T)
    const u16* __restrict__ W2t,    // [320][640] bf16 (W2^T)
    const float* __restrict__ b1g,  // [600]
    const float* __restrict__ b2g,  // [300]
    float* __restrict__ H,          // h_raw [N][320] fp32
    float* __restrict__ st1, float* __restrict__ st2,
    const int M) {

    __shared__ __align__(16) u16 As[128 * ASTR];        // 84.0 KB
    __shared__ __align__(16) u16 Wb[2][320 * HSTR];     // 51.2 KB (slot0: W1 slice [32][ASTR... uses [32][328]; slot1: W2 slice [320][40])
    __shared__ __align__(16) u16 hidT[128 * HSTR];      // 10.2 KB

    const int tid  = threadIdx.x;
    const int bm   = blockIdx.x * 128;
    const int wave = tid >> 6;
    const int lane = tid & 63;
    const int mg   = wave >> 1;       // m-group: rows [mg*32, mg*32+32)
    const int ng   = wave & 1;        // n-half
    const int l15  = lane & 15;
    const int q    = lane >> 4;

    // ---- stage A tile (128 x 320) into LDS, zero-padded past M ----
    #pragma unroll
    for (int it = 0; it < 10; ++it) {
        int u = tid + it * 512;            // 0..5119
        int row = u / 40, ku = u - row * 40;
        uint4 v; v.x = v.y = v.z = v.w = 0;
        if (bm + row < M) v = *(const uint4*)(A + (size_t)(bm + row) * DP + ku * 8);
        *(uint4*)&As[row * ASTR + ku * 8] = v;
    }
    // ---- stage W1 slice c=0 into Wb[0] ----
    {
        uint4 w0 = *(const uint4*)(W1t + (size_t)(tid / 40) * DP + (tid % 40) * 8);
        uint4 w1v = *(const uint4*)(W1t + (size_t)((tid + 512) / 40) * DP + ((tid + 512) % 40) * 8);
        uint4 w2v; w2v.x = w2v.y = w2v.z = w2v.w = 0;
        int u2 = tid + 1024;
        if (u2 < 1280) w2v = *(const uint4*)(W1t + (size_t)(u2 / 40) * DP + (u2 % 40) * 8);
        *(uint4*)&Wb[0][(tid / 40) * ASTR + (tid % 40) * 8] = w0;
        *(uint4*)&Wb[0][((tid + 512) / 40) * ASTR + ((tid + 512) % 40) * 8] = w1v;
        if (u2 < 1280) *(uint4*)&Wb[0][(u2 / 40) * ASTR + (u2 % 40) * 8] = w2v;
    }
    __syncthreads();

    // ---- load A fragments into registers (held for whole kernel) ----
    bf16x8 afr[2][10];
    #pragma unroll
    for (int mf = 0; mf < 2; ++mf)
        #pragma unroll
        for (int kt = 0; kt < 10; ++kt) {
            uint4 t = *(const uint4*)&As[(mg * 32 + mf * 16 + l15) * ASTR + kt * 32 + q * 8];
            afr[mf][kt] = __builtin_bit_cast(bf16x8, t);
        }

    f32x4 acc2[2][10];
    const f32x4 zero4 = {0.f, 0.f, 0.f, 0.f};
    #pragma unroll
    for (int mf = 0; mf < 2; ++mf)
        #pragma unroll
        for (int nf = 0; nf < 10; ++nf) acc2[mf][nf] = zero4;

    // ---- main loop: 20 chunks of 32 hidden columns ----
    for (int c = 0; c < 20; ++c) {
        // prefetch W2 slice c (global -> regs)
        uint4 p0, p1, p2;
        {
            int u0 = tid, u1 = tid + 512, u2 = tid + 1024;
            p0 = *(const uint4*)(W2t + (size_t)(u0 >> 2) * HP + c * 32 + (u0 & 3) * 8);
            p1 = *(const uint4*)(W2t + (size_t)(u1 >> 2) * HP + c * 32 + (u1 & 3) * 8);
            p2.x = p2.y = p2.z = p2.w = 0;
            if (u2 < 1280) p2 = *(const uint4*)(W2t + (size_t)(u2 >> 2) * HP + c * 32 + (u2 & 3) * 8);
        }

        // ---- GEMM1 chunk: acc1 = A(128x320) @ W1slice(32x320)^T ----
        f32x4 acc1[2] = {zero4, zero4};
        #pragma unroll
        for (int kt = 0; kt < 10; ++kt) {
            uint4 t = *(const uint4*)&Wb[0][(ng * 16 + l15) * ASTR + kt * 32 + q * 8];
            bf16x8 bfr = __builtin_bit_cast(bf16x8, t);
            acc1[0] = __builtin_amdgcn_mfma_f32_16x16x32_bf16(afr[0][kt], bfr, acc1[0], 0, 0, 0);
            acc1[1] = __builtin_amdgcn_mfma_f32_16x16x32_bf16(afr[1][kt], bfr, acc1[1], 0, 0, 0);
        }
        // bias + relu -> hidT (bf16)
        {
            int gcol = c * 32 + ng * 16 + l15;
            float bb = (gcol < 600) ? b1g[gcol] : 0.f;
            #pragma unroll
            for (int mf = 0; mf < 2; ++mf)
                #pragma unroll
                for (int r = 0; r < 4; ++r) {
                    float v = fmaxf(acc1[mf][r] + bb, 0.f);
                    hidT[(mg * 32 + mf * 16 + q * 4 + r) * HSTR + ng * 16 + l15] = f2bf(v);
                }
        }
        // write W2 slice into Wb[1]
        {
            int u0 = tid, u1 = tid + 512, u2 = tid + 1024;
            *(uint4*)&Wb[1][(u0 >> 2) * HSTR + (u0 & 3) * 8] = p0;
            *(uint4*)&Wb[1][(u1 >> 2) * HSTR + (u1 & 3) * 8] = p1;
            if (u2 < 1280) *(uint4*)&Wb[1][(u2 >> 2) * HSTR + (u2 & 3) * 8] = p2;
        }
        __syncthreads();

        // prefetch W1 slice c+1
        uint4 q0, q1, q2;
        if (c < 19) {
            int u0 = tid, u1 = tid + 512, u2 = tid + 1024;
            const u16* base = W1t + (size_t)(c + 1) * 32 * DP;
            q0 = *(const uint4*)(base + (size_t)(u0 / 40) * DP + (u0 % 40) * 8);
            q1 = *(const uint4*)(base + (size_t)(u1 / 40) * DP + (u1 % 40) * 8);
            q2.x = q2.y = q2.z = q2.w = 0;
            if (u2 < 1280) q2 = *(const uint4*)(base + (size_t)(u2 / 40) * DP + (u2 % 40) * 8);
        }

        // ---- GEMM2 chunk: acc2 += hid(128x32) @ W2slice(32x320) ----
        bf16x8 a2[2];
        #pragma unroll
        for (int mf = 0; mf < 2; ++mf) {
            uint4 t = *(const uint4*)&hidT[(mg * 32 + mf * 16 + l15) * HSTR + q * 8];
            a2[mf] = __builtin_bit_cast(bf16x8, t);
        }
        #pragma unroll
        for (int nf = 0; nf < 10; ++nf) {
            uint4 t = *(const uint4*)&Wb[1][(ng * 160 + nf * 16 + l15) * HSTR + q * 8];
            bf16x8 bfr = __builtin_bit_cast(bf16x8, t);
            acc2[0][nf] = __builtin_amdgcn_mfma_f32_16x16x32_bf16(a2[0], bfr, acc2[0][nf], 0, 0, 0);
            acc2[1][nf] = __builtin_amdgcn_mfma_f32_16x16x32_bf16(a2[1], bfr, acc2[1][nf], 0, 0, 0);
        }

        // write W1 slice c+1 into Wb[0]
        if (c < 19) {
            int u0 = tid, u1 = tid + 512, u2 = tid + 1024;
            *(uint4*)&Wb[0][(u0 / 40) * ASTR + (u0 % 40) * 8] = q0;
            *(uint4*)&Wb[0][(u1 / 40) * ASTR + (u1 % 40) * 8] = q1;
            if (u2 < 1280) *(uint4*)&Wb[0][(u2 / 40) * ASTR + (u2 % 40) * 8] = q2;
        }
        __syncthreads();
    }

    // ---- epilogue: bias2, store fp32 raw h, BN stats ----
    #pragma unroll
    for (int nf = 0; nf < 10; ++nf) {
        const int col = ng * 160 + nf * 16 + l15;
        const float bb = (col < 300) ? b2g[col] : 0.f;
        float s1 = 0.f, s2 = 0.f;
        #pragma unroll
        for (int mf = 0; mf < 2; ++mf)
            #pragma unroll
            for (int r = 0; r < 4; ++r) {
                const int row = bm + mg * 32 + mf * 16 + q * 4 + r;
                if (row < M) {
                    float v = acc2[mf][nf][r] + bb;
                    H[(size_t)row * DP + col] = v;
                    s1 += v; s2 += v * v;
                }
            }
        s1 += __shfl_xor(s1, 16); s1 += __shfl_xor(s1, 32);
        s2 += __shfl_xor(s2, 16); s2 += __shfl_xor(s2, 32);
        if (q == 0) { atomicAdd(&st1[col], s1); atomicAdd(&st2[col], s2); }
    }
}

// final: d_out[i][d] = scale[d]*raw[i][d] + shift[d]  (no relu, fp32 in/out)
__global__ void finalize(const float* __restrict__ hraw, const float* __restrict__ scale,
                         const float* __restrict__ shift, float* __restrict__ out) {
    const int i = blockIdx.x;
    const int d = threadIdx.x;
    if (d < 300) {
        float x = hraw[(size_t)i * DP + d];
        out[(size_t)i * 300 + d] = fmaf(scale[d], x, shift[d]);
    }
}

// ---------------- launcher ----------------
extern "C" void kernel_launch(void* const* d_in, const int* in_sizes, int n_in,
                              void* d_out, int out_size, void* d_ws, size_t ws_size,
                              hipStream_t stream) {
    const int N = NN, E = EE, L = 5;
    const int*   x     = (const int*)d_in[0];
    const int*   ei    = (const int*)d_in[1];
    const int*   ea    = (const int*)d_in[2];
    const float* at    = (const float*)d_in[3];
    const float* bt    = (const float*)d_in[4];
    const float* w1    = (const float*)d_in[5];
    const float* b1    = (const float*)d_in[6];
    const float* w2    = (const float*)d_in[7];
    const float* b2    = (const float*)d_in[8];
    const float* gamma = (const float*)d_in[9];
    const float* beta  = (const float*)d_in[10];
    float* out = (float*)d_out;

    char* ws = (char*)d_ws;
    size_t off = 0;
    auto alloc = [&](size_t bytes) { char* p = ws + off; off = (off + bytes + 255) & ~(size_t)255; return p; };
    u16* buf_y    = (u16*)alloc((size_t)N * DP * 2);     // post-BN/relu state, bf16
    u16* buf_agg  = (u16*)alloc((size_t)N * DP * 2);
    float* buf_h  = (float*)alloc((size_t)N * DP * 4);   // raw (pre-BN) state, fp32
    u16* w1t      = (u16*)alloc((size_t)5 * HP * DP * 2);
    u16* w2t      = (u16*)alloc((size_t)5 * DP * HP * 2);
    int* deg      = (int*)alloc((size_t)N * 4);
    int* offs     = (int*)alloc((size_t)(N + 1) * 4);
    int* cursors  = (int*)alloc((size_t)N * 4);
    u32* vals     = (u32*)alloc((size_t)E * 4);
    int* bsums    = (int*)alloc(128 * 4);
    float* emb    = (float*)alloc(17 * DP * 4);
    float* stats  = (float*)alloc(2 * DP * 4);
    float* scale  = (float*)alloc(DP * 4);
    float* shift  = (float*)alloc(DP * 4);

    // CSR build (once per call; reused by all 5 layers)
    (void)hipMemsetAsync(deg, 0, (size_t)N * 4, stream);
    count_deg<<<(E + 255) / 256, 256, 0, stream>>>(ei, deg, E);
    const int nb = (N + 1023) / 1024;
    scan1<<<nb, 1024, 0, stream>>>(deg, offs, bsums, N);
    scan2<<<1, 128, 0, stream>>>(bsums, nb);
    scan3<<<(N + 1 + 1023) / 1024, 1024, 0, stream>>>(offs, bsums, N, E);
    (void)hipMemcpyAsync(cursors, offs, (size_t)N * 4, hipMemcpyDeviceToDevice, stream);
    fill_csr<<<(E + 255) / 256, 256, 0, stream>>>(ei, ea, cursors, vals, E);

    // weights -> bf16 transposed padded
    conv_w1<<<(5 * HP * DP + 255) / 256, 256, 0, stream>>>(w1, w1t);
    conv_w2<<<(5 * DP * HP + 255) / 256, 256, 0, stream>>>(w2, w2t);

    // layer-0 state
    atom_enc<<<N, DP, 0, stream>>>(x, at, buf_y);

    const int MB = (N + 127) / 128; // 782
    for (int l = 0; l < L; ++l) {
        bond_enc<<<17, DP, 0, stream>>>(bt + (size_t)l * 4 * 6 * 300, emb);
        aggregate<<<(N * 64 + 255) / 256, 256, 0, stream>>>(
            buf_y, emb, offs, vals, buf_agg, N);
        (void)hipMemsetAsync(stats, 0, 2 * DP * 4, stream);
        fused_mlp<<<MB, 512, 0, stream>>>(
            buf_agg,
            w1t + (size_t)l * HP * DP, w2t + (size_t)l * DP * HP,
            b1 + (size_t)l * 600, b2 + (size_t)l * 300,
            buf_h, stats, stats + DP, N);
        bn_ss<<<1, DP, 0, stream>>>(stats, gamma + (size_t)l * 300, beta + (size_t)l * 300, scale, shift, N);
        if (l < L - 1)
            bn_apply<<<N, DP, 0, stream>>>(buf_h, scale, shift, buf_y);
    }
    finalize<<<N, DP, 0, stream>>>(buf_h, scale, shift, out);
}